// Round 17
// baseline (104.038 us; speedup 1.0000x reference)
//
#include <hip/hip_runtime.h>
#include <hip/hip_bf16.h>

typedef __bf16 bf16x8 __attribute__((ext_vector_type(8)));
typedef float  f32x4  __attribute__((ext_vector_type(4)));
typedef float  f32x16 __attribute__((ext_vector_type(16)));

// async 16B global -> LDS (wave-uniform LDS base + lane*16)
__device__ __forceinline__ void gload_lds16(const void* g, void* l) {
  __builtin_amdgcn_global_load_lds(
      (const __attribute__((address_space(1))) unsigned int*)g,
      (__attribute__((address_space(3))) unsigned int*)l, 16, 0, 0);
}

// XCD-aware bijective remap for a (16, 32) xy-grid: blocks sharing y land on ONE XCD.
__device__ __forceinline__ void xcd_remap(int& x, int& y) {
  const int lin = blockIdx.x + (blockIdx.y << 4);   // 0..511
  const int xcd = lin & 7, slot = lin >> 3;         // slot 0..63
  y = ((slot >> 4) << 3) + xcd;                     // 0..31
  x = slot & 15;                                    // 0..15
}

// ---------------- fp32 -> bf16 convert (vectorized) ----------------
__global__ void k_cvt(const float* __restrict__ s, __bf16* __restrict__ d, int n4) {
  int i = blockIdx.x * blockDim.x + threadIdx.x;
  if (i >= n4) return;
  float4 v = ((const float4*)s)[i];
  union { __bf16 h[4]; uint2 u; } o;
  o.h[0] = (__bf16)v.x; o.h[1] = (__bf16)v.y;
  o.h[2] = (__bf16)v.z; o.h[3] = (__bf16)v.w;
  ((uint2*)d)[i] = o.u;
}

// ---------------- C[M,N] = A[M,K] @ B[N,K]^T + bias ----------------
// BK=64 (16 fat iters), 3 buffers, stage-AFTER-barrier, counted vmcnt(6).
// Race audit: stage of tile t+2 -> buf (t+2)%3 happens post-barrier-t, when all
// waves have finished compute t-1; readers of buf t%3 are concurrent but target
// differs; tile t+3 -> buf t%3 can only be staged after barrier t+1, which all
// waves reach only after finishing compute t. vmcnt(6) pre-barrier retires tile t.
// Per-buffer layout: [2][128x32] k-slices -> proven conflict-free frag reads.
template<bool OUT_BF16>
__global__ __launch_bounds__(256, 2)
void k_gemm_bt(const __bf16* __restrict__ A, const __bf16* __restrict__ B,
               const float* __restrict__ bias, void* __restrict__ C,
               int M, int N, int K) {
  __shared__ __align__(16) __bf16 At[3][2][128 * 32];   // 48KB
  __shared__ __align__(16) __bf16 Bt[3][2][64 * 32];    // 24KB
  const int tid  = threadIdx.x;
  const int lane = tid & 63;
  const int w    = tid >> 6;
  const int wr   = w >> 1, wc = w & 1;
  int bx, by; xcd_remap(bx, by);
  const int bm = by * 128, bn = bx * 64;

  f32x4 acc[4][2] = {};

  const __bf16* ga = A + (size_t)(bm + (tid >> 2)) * K + (tid & 3) * 8;
  const __bf16* gb = B + (size_t)(bn + (tid >> 2)) * K + (tid & 3) * 8;

#define STAGE_TILE(buf, k0)                                                     \
  gload_lds16(ga + (k0),                       &At[buf][0][(w * 16) * 32]);     \
  gload_lds16(ga + (k0) + (size_t)64 * K,      &At[buf][0][(64 + w * 16) * 32]);\
  gload_lds16(ga + (k0) + 32,                  &At[buf][1][(w * 16) * 32]);     \
  gload_lds16(ga + (k0) + 32 + (size_t)64 * K, &At[buf][1][(64 + w * 16) * 32]);\
  gload_lds16(gb + (k0),                       &Bt[buf][0][(w * 16) * 32]);     \
  gload_lds16(gb + (k0) + 32,                  &Bt[buf][1][(w * 16) * 32]);

  // prologue: tiles 0,1 -> buffers 0,1 (12 ops in flight)
  STAGE_TILE(0, 0)
  STAGE_TILE(1, 64)

  const int NIT = K / 64;                      // 16
  for (int it = 0; it < NIT; ++it) {
    const int cur = it % 3;
    if (it + 2 < NIT) {
      asm volatile("s_waitcnt vmcnt(6)" ::: "memory");   // tile it retired; it+1 in flight
    } else if (it + 2 == NIT) {
      asm volatile("s_waitcnt vmcnt(6)" ::: "memory");
    } else {
      asm volatile("s_waitcnt vmcnt(0)" ::: "memory");
    }
    __builtin_amdgcn_s_barrier();
    __builtin_amdgcn_sched_barrier(0);
    if (it + 2 < NIT) {                                  // stage AFTER barrier
      const int sb = (it + 2) % 3;
      const int k2 = (it + 2) * 64;
      STAGE_TILE(sb, k2)
    }

    bf16x8 a[2][4], b[2][2];
#pragma unroll
    for (int sl = 0; sl < 2; ++sl) {
#pragma unroll
      for (int mt = 0; mt < 4; ++mt)
        a[sl][mt] = *(const bf16x8*)&At[cur][sl][(wr * 64 + mt * 16 + (lane & 15)) * 32 + (lane >> 4) * 8];
#pragma unroll
      for (int nt = 0; nt < 2; ++nt)
        b[sl][nt] = *(const bf16x8*)&Bt[cur][sl][(wc * 32 + nt * 16 + (lane & 15)) * 32 + (lane >> 4) * 8];
    }
    __builtin_amdgcn_s_setprio(1);
#pragma unroll
    for (int sl = 0; sl < 2; ++sl)
#pragma unroll
      for (int mt = 0; mt < 4; ++mt)
#pragma unroll
        for (int nt = 0; nt < 2; ++nt)
          acc[mt][nt] = __builtin_amdgcn_mfma_f32_16x16x32_bf16(a[sl][mt], b[sl][nt], acc[mt][nt], 0, 0, 0);
    __builtin_amdgcn_s_setprio(0);
  }
#undef STAGE_TILE

#pragma unroll
  for (int nt = 0; nt < 2; ++nt) {
    const int col = bn + wc * 32 + nt * 16 + (lane & 15);
    const float bv = bias[col];
#pragma unroll
    for (int mt = 0; mt < 4; ++mt) {
#pragma unroll
      for (int r = 0; r < 4; ++r) {
        const int row = bm + wr * 64 + mt * 16 + (lane >> 4) * 4 + r;
        const float v = acc[mt][nt][r] + bv;
        if (OUT_BF16) ((__bf16*)C)[(size_t)row * N + col] = (__bf16)v;
        else          ((float*)C)[(size_t)row * N + col]  = v;
      }
    }
  }
}

// ---------------- flash attention (Q = K = V), 32x32x16, z-split, half-tile ----------------
// r16 proven math, loop-fissioned into two 32-kv halves so peak live acc = O(32) +
// s(16) = 48 regs; total unified ~118 <= 128 -> launch_bounds(256,4) without spill
// -> 4 waves/SIMD. z-split (grid *2) supplies 4 blocks/CU. No-max softmax ->
// merge needs only l. lsum shfl deferred to epilogue.
#define SWZ2(row, col) ((row) * 64 + ((col) ^ (((((row) & 7) ^ ((row) >> 3)) & 7) << 3)))

#define ATTN_TILE(T, KB, VB)                                                  \
  {                                                                           \
    *(bf16x8*)&KB[SWZ2(2 * sm, c0)]     = v0;                                 \
    *(bf16x8*)&KB[SWZ2(2 * sm + 1, c0)] = v1;                                 \
    _Pragma("unroll")                                                         \
    for (int j = 0; j < 8; ++j) {                                             \
      union { __bf16 b[2]; unsigned u; } pk;                                  \
      pk.b[0] = v0[j]; pk.b[1] = v1[j];                                       \
      *(unsigned*)&VB[SWZ2(c0 + j, 2 * sm)] = pk.u;                           \
    }                                                                         \
    __syncthreads();                                                          \
    if ((T) < 15) {                                                           \
      v0 = *(const bf16x8*)&gsrc[(size_t)((T) + 1) * 64 * 1024];              \
      v1 = *(const bf16x8*)&gsrc[(size_t)((T) + 1) * 64 * 1024 + 1024];       \
    }                                                                         \
    _Pragma("unroll")                                                         \
    for (int kvf = 0; kvf < 2; ++kvf) {                                       \
      f32x16 s = {};                                                          \
      __builtin_amdgcn_s_setprio(1);                                          \
      _Pragma("unroll")                                                       \
      for (int ks = 0; ks < 4; ++ks) {                                        \
        bf16x8 ka = *(const bf16x8*)&KB[SWZ2(kvf * 32 + l31, ks * 16 + h * 8)]; \
        s = __builtin_amdgcn_mfma_f32_32x32x16_bf16(ka, qb[ks], s, 0, 0, 0);  \
      }                                                                       \
      __builtin_amdgcn_s_setprio(0);                                          \
      unsigned P[4][2];                                                       \
      _Pragma("unroll")                                                       \
      for (int rq = 0; rq < 4; ++rq) {                                        \
        _Pragma("unroll")                                                     \
        for (int tt = 0; tt < 2; ++tt) {                                      \
          const float p0 = __builtin_amdgcn_exp2f(s[rq * 4 + tt * 2]);        \
          const float p1 = __builtin_amdgcn_exp2f(s[rq * 4 + tt * 2 + 1]);    \
          if (tt == 0) { ls0 += p0; ls1 += p1; } else { ls2 += p0; ls3 += p1; } \
          union { __bf16 b[2]; unsigned u; } pk;                              \
          pk.b[0] = (__bf16)p0; pk.b[1] = (__bf16)p1;                         \
          P[rq][tt] = pk.u;                                                   \
        }                                                                     \
      }                                                                       \
      _Pragma("unroll")                                                       \
      for (int ko = 0; ko < 2; ++ko) {                                        \
        asm volatile("v_permlane32_swap_b32 %0, %1"                           \
                     : "+v"(P[ko * 2][0]), "+v"(P[ko * 2 + 1][0]));           \
        asm volatile("v_permlane32_swap_b32 %0, %1"                           \
                     : "+v"(P[ko * 2][1]), "+v"(P[ko * 2 + 1][1]));           \
      }                                                                       \
      __builtin_amdgcn_s_setprio(1);                                          \
      _Pragma("unroll")                                                       \
      for (int dh = 0; dh < 2; ++dh) {                                        \
        _Pragma("unroll")                                                     \
        for (int ko = 0; ko < 2; ++ko) {                                      \
          union { unsigned u[4]; bf16x8 v; } pu;                              \
          pu.u[0] = P[ko * 2][0];     pu.u[1] = P[ko * 2][1];                 \
          pu.u[2] = P[ko * 2 + 1][0]; pu.u[3] = P[ko * 2 + 1][1];             \
          bf16x8 vb = *(const bf16x8*)&VB[SWZ2(dh * 32 + l31, (kvf * 2 + ko) * 16 + h * 8)]; \
          O[dh] = __builtin_amdgcn_mfma_f32_32x32x16_bf16(pu.v, vb, O[dh], 0, 0, 0); \
        }                                                                     \
      }                                                                       \
      __builtin_amdgcn_s_setprio(0);                                          \
    }                                                                         \
  }

__global__ __launch_bounds__(256, 4)
void k_attn(const __bf16* __restrict__ q, __bf16* __restrict__ op,
            float* __restrict__ ml) {
  __shared__ __align__(16) __bf16 Kt[2][64 * 64];
  __shared__ __align__(16) __bf16 Vt[2][64 * 64];
  const int tid = threadIdx.x, lane = tid & 63;
  const int w = tid >> 6;
  const int l31 = lane & 31, h = lane >> 5;
  const int z = blockIdx.z;
  int bqx, bh; xcd_remap(bqx, bh);
  const size_t base = ((size_t)(bh >> 4) * 2048) * 1024 + (bh & 15) * 64;
  const int q0 = bqx * 128 + w * 32;
  const float c2 = 0.18033688f;     // 0.125 * log2(e)

  // Q B-frags, PRE-SCALED by c2
  bf16x8 qb[4];
#pragma unroll
  for (int ks = 0; ks < 4; ++ks) {
    union { bf16x8 v; __bf16 b[8]; } u;
    u.v = *(const bf16x8*)&q[base + (size_t)(q0 + l31) * 1024 + ks * 16 + h * 8];
#pragma unroll
    for (int j = 0; j < 8; ++j) u.b[j] = (__bf16)((float)u.b[j] * c2);
    qb[ks] = u.v;
  }

  f32x16 O[2] = {};
  float ls0 = 0.f, ls1 = 0.f, ls2 = 0.f, ls3 = 0.f;

  // staging: thread covers kv rows 2sm, 2sm+1 (within this z-half), cols c0..c0+7
  const int sm = tid >> 3, c0 = (tid & 7) * 8;
  const __bf16* gsrc = q + base + (size_t)(z * 1024 + 2 * sm) * 1024 + c0;

  __bf16* const K0 = &Kt[0][0];  __bf16* const V0 = &Vt[0][0];
  __bf16* const K1 = &Kt[1][0];  __bf16* const V1 = &Vt[1][0];

  bf16x8 v0 = *(const bf16x8*)&gsrc[0];
  bf16x8 v1 = *(const bf16x8*)&gsrc[1024];

  for (int t2 = 0; t2 < 8; ++t2) {
    ATTN_TILE(2 * t2,     K0, V0)
    ATTN_TILE(2 * t2 + 1, K1, V1)
  }

  // ---- epilogue: deferred l reduction, normalized partial O + l out
  float l_run = (ls0 + ls1) + (ls2 + ls3);
  l_run += __shfl_xor(l_run, 32);
  const float linv = 1.0f / l_run;
  if (h == 0) ml[z * 65536 + bh * 2048 + (q0 + l31)] = l_run;
  __bf16* opz = op + (size_t)z * 4194304;
#pragma unroll
  for (int r = 0; r < 16; ++r) {
    const int qrow = (r & 3) + 8 * (r >> 2) + 4 * h;
    const float rs = __shfl(linv, qrow);
    opz[base + (size_t)(q0 + qrow) * 1024 + l31]      = (__bf16)(O[0][r] * rs);
    opz[base + (size_t)(q0 + qrow) * 1024 + 32 + l31] = (__bf16)(O[1][r] * rs);
  }
}

// ---------------- merge the two KV halves (no-max: weights = l) ----------------
__global__ __launch_bounds__(256)
void k_merge(const __bf16* __restrict__ op, const float* __restrict__ ml,
             __bf16* __restrict__ out) {
  const int idx = blockIdx.x * 256 + threadIdx.x;        // 524288 threads
  const int d8 = idx & 7, hh = (idx >> 3) & 15, row = idx >> 7;   // row 0..4095
  const int b = row >> 11, s = row & 2047;
  const int mli = (b * 16 + hh) * 2048 + s;
  const float lA = ml[mli], lB = ml[65536 + mli];
  const float inv = 1.0f / (lA + lB);
  const float fA = lA * inv, fB = lB * inv;
  const size_t off = (size_t)row * 1024 + hh * 64 + d8 * 8;
  bf16x8 a = *(const bf16x8*)&op[off];
  bf16x8 c = *(const bf16x8*)&op[4194304 + off];
  union { __bf16 h[8]; bf16x8 v; } r;
#pragma unroll
  for (int j = 0; j < 8; ++j)
    r.h[j] = (__bf16)((float)a[j] * fA + (float)c[j] * fB);
  *(bf16x8*)&out[off] = r.v;
}

// ---------------- launch ----------------
extern "C" void kernel_launch(void* const* d_in, const int* in_sizes, int n_in,
                              void* d_out, int out_size, void* d_ws, size_t ws_size,
                              hipStream_t stream) {
  const float* x  = (const float*)d_in[0];
  const float* Wq = (const float*)d_in[1];
  const float* bq = (const float*)d_in[2];
  const float* Wo = (const float*)d_in[3];
  const float* bo = (const float*)d_in[4];

  char* ws = (char*)d_ws;
  __bf16* xb    = (__bf16*)(ws);                        // [0,8)   x bf16
  __bf16* ab    = (__bf16*)(ws);                        // [0,8)   merged attn out (aliases xb)
  __bf16* wqb   = (__bf16*)(ws + ((size_t)8  << 20));   // [8,10)
  __bf16* wob   = (__bf16*)(ws + ((size_t)10 << 20));   // [10,12)
  __bf16* qb    = (__bf16*)(ws + ((size_t)12 << 20));   // [12,20) q projection
  __bf16* opart = (__bf16*)(ws + ((size_t)20 << 20));   // [20,36) partial O (2 halves)
  float*  mlbuf = (float*) (ws + ((size_t)36 << 20));   // [36,36.5) l sums

  const int M = 4096, N = 1024, K = 1024;

  k_cvt<<<(M * K / 4 + 255) / 256, 256, 0, stream>>>(x,  xb,  M * K / 4);
  k_cvt<<<(N * K / 4 + 255) / 256, 256, 0, stream>>>(Wq, wqb, N * K / 4);
  k_cvt<<<(N * K / 4 + 255) / 256, 256, 0, stream>>>(Wo, wob, N * K / 4);

  k_gemm_bt<true ><<<dim3(16, 32), 256, 0, stream>>>(xb, wqb, bq, qb, M, N, K);
  k_attn          <<<dim3(16, 32, 2), 256, 0, stream>>>(qb, opart, mlbuf);
  k_merge         <<<2048, 256, 0, stream>>>(opart, mlbuf, ab);
  k_gemm_bt<false><<<dim3(16, 32), 256, 0, stream>>>(ab, wob, bo, d_out, M, N, K);
}

// Round 18
// 98.557 us; speedup vs baseline: 1.0556x; 1.0556x over previous
//
#include <hip/hip_runtime.h>
#include <hip/hip_bf16.h>

typedef __bf16 bf16x8 __attribute__((ext_vector_type(8)));
typedef float  f32x4  __attribute__((ext_vector_type(4)));
typedef float  f32x16 __attribute__((ext_vector_type(16)));

// async 16B global -> LDS (wave-uniform LDS base + lane*16)
__device__ __forceinline__ void gload_lds16(const void* g, void* l) {
  __builtin_amdgcn_global_load_lds(
      (const __attribute__((address_space(1))) unsigned int*)g,
      (__attribute__((address_space(3))) unsigned int*)l, 16, 0, 0);
}

// XCD-aware bijective remap for a (16, 32) grid: blocks sharing y land on ONE XCD.
__device__ __forceinline__ void xcd_remap(int& x, int& y) {
  const int lin = blockIdx.x + (blockIdx.y << 4);   // 0..511
  const int xcd = lin & 7, slot = lin >> 3;         // slot 0..63
  y = ((slot >> 4) << 3) + xcd;                     // 0..31
  x = slot & 15;                                    // 0..15
}

// ---------------- fp32 -> bf16 convert (vectorized) ----------------
__global__ void k_cvt(const float* __restrict__ s, __bf16* __restrict__ d, int n4) {
  int i = blockIdx.x * blockDim.x + threadIdx.x;
  if (i >= n4) return;
  float4 v = ((const float4*)s)[i];
  union { __bf16 h[4]; uint2 u; } o;
  o.h[0] = (__bf16)v.x; o.h[1] = (__bf16)v.y;
  o.h[2] = (__bf16)v.z; o.h[3] = (__bf16)v.w;
  ((uint2*)d)[i] = o.u;
}

// ---------------- C[M,N] = A[M,K] @ B[N,K]^T + bias ----------------
// r16 proven: 4 buffers BK=32, depth-2 counted vmcnt(6), one raw barrier/iter,
// XCD swizzle (same-bm blocks share one XCD's L2 A-panel).
template<bool OUT_BF16>
__global__ __launch_bounds__(256, 2)
void k_gemm_bt(const __bf16* __restrict__ A, const __bf16* __restrict__ B,
               const float* __restrict__ bias, void* __restrict__ C,
               int M, int N, int K) {
  __shared__ __align__(16) __bf16 At[4][128 * 32];   // 32KB
  __shared__ __align__(16) __bf16 Bt[4][64 * 32];    // 16KB
  const int tid  = threadIdx.x;
  const int lane = tid & 63;
  const int w    = tid >> 6;
  const int wr   = w >> 1, wc = w & 1;
  int bx, by; xcd_remap(bx, by);
  const int bm = by * 128, bn = bx * 64;

  f32x4 acc[4][2] = {};

  const __bf16* ga = A + (size_t)(bm + (tid >> 2)) * K + (tid & 3) * 8;
  const __bf16* gb = B + (size_t)(bn + (tid >> 2)) * K + (tid & 3) * 8;

#pragma unroll
  for (int p = 0; p < 2; ++p) {
    gload_lds16(ga + p * 32,                  &At[p][(w * 16) * 32]);
    gload_lds16(ga + p * 32 + (size_t)64 * K, &At[p][(64 + w * 16) * 32]);
    gload_lds16(gb + p * 32,                  &Bt[p][(w * 16) * 32]);
  }

  const int NIT = K / 32;                      // 32
  for (int it = 0; it < NIT; ++it) {
    const int cur = it & 3;
    if (it + 2 < NIT) {
      const int nb = (it + 2) & 3;
      const int k2 = (it + 2) * 32;
      gload_lds16(ga + k2,                  &At[nb][(w * 16) * 32]);
      gload_lds16(ga + k2 + (size_t)64 * K, &At[nb][(64 + w * 16) * 32]);
      gload_lds16(gb + k2,                  &Bt[nb][(w * 16) * 32]);
      asm volatile("s_waitcnt vmcnt(6)" ::: "memory");
    } else if (it + 2 == NIT) {
      asm volatile("s_waitcnt vmcnt(3)" ::: "memory");
    } else {
      asm volatile("s_waitcnt vmcnt(0)" ::: "memory");
    }
    __builtin_amdgcn_s_barrier();
    __builtin_amdgcn_sched_barrier(0);

    bf16x8 a[4], b[2];
#pragma unroll
    for (int mt = 0; mt < 4; ++mt)
      a[mt] = *(const bf16x8*)&At[cur][(wr * 64 + mt * 16 + (lane & 15)) * 32 + (lane >> 4) * 8];
#pragma unroll
    for (int nt = 0; nt < 2; ++nt)
      b[nt] = *(const bf16x8*)&Bt[cur][(wc * 32 + nt * 16 + (lane & 15)) * 32 + (lane >> 4) * 8];
    __builtin_amdgcn_s_setprio(1);
#pragma unroll
    for (int mt = 0; mt < 4; ++mt)
#pragma unroll
      for (int nt = 0; nt < 2; ++nt)
        acc[mt][nt] = __builtin_amdgcn_mfma_f32_16x16x32_bf16(a[mt], b[nt], acc[mt][nt], 0, 0, 0);
    __builtin_amdgcn_s_setprio(0);
  }

#pragma unroll
  for (int nt = 0; nt < 2; ++nt) {
    const int col = bn + wc * 32 + nt * 16 + (lane & 15);
    const float bv = bias[col];
#pragma unroll
    for (int mt = 0; mt < 4; ++mt) {
#pragma unroll
      for (int r = 0; r < 4; ++r) {
        const int row = bm + wr * 64 + mt * 16 + (lane >> 4) * 4 + r;
        const float v = acc[mt][nt][r] + bv;
        if (OUT_BF16) ((__bf16*)C)[(size_t)row * N + col] = (__bf16)v;
        else          ((float*)C)[(size_t)row * N + col]  = v;
      }
    }
  }
}

// ---------------- flash attention (Q = K = V), 32x32x16 MFMA ----------------
// r16 proven single-pass body, with the lsum reduction MOVED TO THE MFMA PIPE:
// Osum = mfma(P_frag, ones, Osum) accumulates row-sums of P (4 extra MFMA/tile)
// replacing 32 VALU adds + mux + the entire epilogue l-shuffle chain (Osum's
// C-layout row mapping equals O's, so lane-local 1/Osum[r] normalizes directly).
// l now derives from the same bf16 P as O (more consistent normalization).
#define SWZ2(row, col) ((row) * 64 + ((col) ^ (((((row) & 7) ^ ((row) >> 3)) & 7) << 3)))

#define ATTN_TILE(T, KB, VB)                                                  \
  {                                                                           \
    *(bf16x8*)&KB[SWZ2(2 * sm, c0)]     = v0;                                 \
    *(bf16x8*)&KB[SWZ2(2 * sm + 1, c0)] = v1;                                 \
    _Pragma("unroll")                                                         \
    for (int j = 0; j < 8; ++j) {                                             \
      union { __bf16 b[2]; unsigned u; } pk;                                  \
      pk.b[0] = v0[j]; pk.b[1] = v1[j];                                       \
      *(unsigned*)&VB[SWZ2(c0 + j, 2 * sm)] = pk.u;                           \
    }                                                                         \
    __syncthreads();                                                          \
    if ((T) < 31) {                                                           \
      v0 = *(const bf16x8*)&gsrc[(size_t)((T) + 1) * 64 * 1024];              \
      v1 = *(const bf16x8*)&gsrc[(size_t)((T) + 1) * 64 * 1024 + 1024];       \
    }                                                                         \
    f32x16 s[2] = {};                                                         \
    _Pragma("unroll")                                                         \
    for (int kvf = 0; kvf < 2; ++kvf) {                                       \
      __builtin_amdgcn_s_setprio(1);                                          \
      _Pragma("unroll")                                                       \
      for (int ks = 0; ks < 4; ++ks) {                                        \
        bf16x8 ka = *(const bf16x8*)&KB[SWZ2(kvf * 32 + l31, ks * 16 + h * 8)]; \
        s[kvf] = __builtin_amdgcn_mfma_f32_32x32x16_bf16(ka, qb[ks], s[kvf], 0, 0, 0); \
      }                                                                       \
      __builtin_amdgcn_s_setprio(0);                                          \
    }                                                                         \
    unsigned P[2][4][2];                                                      \
    _Pragma("unroll")                                                         \
    for (int kvf = 0; kvf < 2; ++kvf) {                                       \
      _Pragma("unroll")                                                       \
      for (int rq = 0; rq < 4; ++rq) {                                        \
        _Pragma("unroll")                                                     \
        for (int tt = 0; tt < 2; ++tt) {                                      \
          const float p0 = __builtin_amdgcn_exp2f(s[kvf][rq * 4 + tt * 2]);   \
          const float p1 = __builtin_amdgcn_exp2f(s[kvf][rq * 4 + tt * 2 + 1]); \
          union { __bf16 b[2]; unsigned u; } pk;                              \
          pk.b[0] = (__bf16)p0; pk.b[1] = (__bf16)p1;                         \
          P[kvf][rq][tt] = pk.u;                                              \
        }                                                                     \
      }                                                                       \
    }                                                                         \
    _Pragma("unroll")                                                         \
    for (int ko = 0; ko < 4; ++ko) {                                          \
      const int kvf = ko >> 1, rqa = (ko & 1) * 2, rqb = rqa + 1;             \
      asm volatile("v_permlane32_swap_b32 %0, %1"                             \
                   : "+v"(P[kvf][rqa][0]), "+v"(P[kvf][rqb][0]));             \
      asm volatile("v_permlane32_swap_b32 %0, %1"                             \
                   : "+v"(P[kvf][rqa][1]), "+v"(P[kvf][rqb][1]));             \
    }                                                                         \
    __builtin_amdgcn_s_setprio(1);                                            \
    _Pragma("unroll")                                                         \
    for (int ko = 0; ko < 4; ++ko) {                                          \
      const int kvf = ko >> 1, rqa = (ko & 1) * 2, rqb = rqa + 1;             \
      union { unsigned u[4]; bf16x8 v; } pu;                                  \
      pu.u[0] = P[kvf][rqa][0]; pu.u[1] = P[kvf][rqa][1];                     \
      pu.u[2] = P[kvf][rqb][0]; pu.u[3] = P[kvf][rqb][1];                     \
      Osum = __builtin_amdgcn_mfma_f32_32x32x16_bf16(pu.v, onesb, Osum, 0, 0, 0); \
      bf16x8 vb0 = *(const bf16x8*)&VB[SWZ2(l31,      ko * 16 + h * 8)];      \
      bf16x8 vb1 = *(const bf16x8*)&VB[SWZ2(32 + l31, ko * 16 + h * 8)];      \
      O[0] = __builtin_amdgcn_mfma_f32_32x32x16_bf16(pu.v, vb0, O[0], 0, 0, 0); \
      O[1] = __builtin_amdgcn_mfma_f32_32x32x16_bf16(pu.v, vb1, O[1], 0, 0, 0); \
    }                                                                         \
    __builtin_amdgcn_s_setprio(0);                                            \
  }

__global__ __launch_bounds__(256, 2)
void k_attn(const __bf16* __restrict__ q, __bf16* __restrict__ o) {
  __shared__ __align__(16) __bf16 Kt[2][64 * 64];
  __shared__ __align__(16) __bf16 Vt[2][64 * 64];
  const int tid = threadIdx.x, lane = tid & 63;
  const int w = tid >> 6;
  const int l31 = lane & 31, h = lane >> 5;
  int bqx, bh; xcd_remap(bqx, bh);
  const size_t base = ((size_t)(bh >> 4) * 2048) * 1024 + (bh & 15) * 64;
  const int q0 = bqx * 128 + w * 32;
  const float c2 = 0.18033688f;     // 0.125 * log2(e)

  // ones B-operand for the row-sum MFMA
  union { unsigned u[4]; bf16x8 v; } ones_u;
  ones_u.u[0] = 0x3F803F80u; ones_u.u[1] = 0x3F803F80u;
  ones_u.u[2] = 0x3F803F80u; ones_u.u[3] = 0x3F803F80u;
  const bf16x8 onesb = ones_u.v;

  // Q B-frags, PRE-SCALED by c2: col q = q0+l31, k(d) = 16ks + 8h + 0..7
  bf16x8 qb[4];
#pragma unroll
  for (int ks = 0; ks < 4; ++ks) {
    union { bf16x8 v; __bf16 b[8]; } u;
    u.v = *(const bf16x8*)&q[base + (size_t)(q0 + l31) * 1024 + ks * 16 + h * 8];
#pragma unroll
    for (int j = 0; j < 8; ++j) u.b[j] = (__bf16)((float)u.b[j] * c2);
    qb[ks] = u.v;
  }

  f32x16 O[2] = {};                 // row q=(reg&3)+8*(reg>>2)+4h, col d=32dh+l31
  f32x16 Osum = {};                 // same row mapping; all cols identical = row-sum of P

  // staging: thread covers kv rows 2sm, 2sm+1, cols c0..c0+7
  const int sm = tid >> 3, c0 = (tid & 7) * 8;
  const __bf16* gsrc = q + base + (size_t)(2 * sm) * 1024 + c0;

  __bf16* const K0 = &Kt[0][0];  __bf16* const V0 = &Vt[0][0];
  __bf16* const K1 = &Kt[1][0];  __bf16* const V1 = &Vt[1][0];

  // prologue: tile 0 into registers
  bf16x8 v0 = *(const bf16x8*)&gsrc[0];
  bf16x8 v1 = *(const bf16x8*)&gsrc[1024];

  for (int t2 = 0; t2 < 16; ++t2) {
    ATTN_TILE(2 * t2,     K0, V0)
    ATTN_TILE(2 * t2 + 1, K1, V1)
  }

  // ---- epilogue: O / Osum (lane-local; Osum row mapping == O row mapping)
#pragma unroll
  for (int r = 0; r < 16; ++r) {
    const int qrow = (r & 3) + 8 * (r >> 2) + 4 * h;
    const float rs = 1.0f / Osum[r];
    o[base + (size_t)(q0 + qrow) * 1024 + l31]      = (__bf16)(O[0][r] * rs);
    o[base + (size_t)(q0 + qrow) * 1024 + 32 + l31] = (__bf16)(O[1][r] * rs);
  }
}

// ---------------- launch ----------------
extern "C" void kernel_launch(void* const* d_in, const int* in_sizes, int n_in,
                              void* d_out, int out_size, void* d_ws, size_t ws_size,
                              hipStream_t stream) {
  const float* x  = (const float*)d_in[0];
  const float* Wq = (const float*)d_in[1];
  const float* bq = (const float*)d_in[2];
  const float* Wo = (const float*)d_in[3];
  const float* bo = (const float*)d_in[4];

  char* ws = (char*)d_ws;
  __bf16* xb  = (__bf16*)(ws);                          // [0,8)   x bf16
  __bf16* ab  = (__bf16*)(ws);                          // [0,8)   attn out (aliases xb; xb dead)
  __bf16* wqb = (__bf16*)(ws + ((size_t)8  << 20));     // [8,10)
  __bf16* wob = (__bf16*)(ws + ((size_t)10 << 20));     // [10,12)
  __bf16* qb  = (__bf16*)(ws + ((size_t)12 << 20));     // [12,20) q projection

  const int M = 4096, N = 1024, K = 1024;

  k_cvt<<<(M * K / 4 + 255) / 256, 256, 0, stream>>>(x,  xb,  M * K / 4);
  k_cvt<<<(N * K / 4 + 255) / 256, 256, 0, stream>>>(Wq, wqb, N * K / 4);
  k_cvt<<<(N * K / 4 + 255) / 256, 256, 0, stream>>>(Wo, wob, N * K / 4);

  k_gemm_bt<true ><<<dim3(16, 32), 256, 0, stream>>>(xb, wqb, bq, qb, M, N, K);
  k_attn          <<<dim3(16, 32), 256, 0, stream>>>(qb, ab);
  k_gemm_bt<false><<<dim3(16, 32), 256, 0, stream>>>(ab, wob, bo, d_out, M, N, K);
}